// Round 1
// baseline (782.807 us; speedup 1.0000x reference)
//
#include <hip/hip_runtime.h>

typedef unsigned short ushort_t;
typedef unsigned long long u64;
typedef short short8 __attribute__((ext_vector_type(8)));
typedef float f32x4 __attribute__((ext_vector_type(4)));

#define B_   32
#define C_   64
#define T_   12
#define N_   1024
#define KS_  3
#define KC_  (KS_*N_)        // 3072
#define RPB  (T_*C_)         // 768 rows per batch in Y

__device__ __forceinline__ float bf2f(ushort_t u) {
  union { unsigned u; float f; } v; v.u = ((unsigned)u) << 16; return v.f;
}
__device__ __forceinline__ ushort_t f2bf(float f) {
  union { float f; unsigned u; } v; v.f = f;
  unsigned r = v.u + 0x7FFFu + ((v.u >> 16) & 1u);
  return (ushort_t)(r >> 16);
}

__device__ __forceinline__ void gload16(const ushort_t* g, ushort_t* l) {
  __builtin_amdgcn_global_load_lds(
      (const __attribute__((address_space(1))) unsigned int*)g,
      (__attribute__((address_space(3))) unsigned int*)l, 16, 0, 0);
}

// ---------- prep: theta pack  thp[l][i][k*64+o] = bf16(theta_l[i][o][k]) ----------
__global__ void prep_th(const float* __restrict__ th1, const float* __restrict__ th2,
                        ushort_t* __restrict__ out) {
  int id = blockIdx.x * 256 + threadIdx.x;          // 2*64*192 = 24576
  if (id >= 2 * 64 * 192) return;
  int l = id / 12288, rem = id % 12288;
  int i = rem / 192, kk = rem % 192;
  int k = kk >> 6, o = kk & 63;
  const float* th = l ? th2 : th1;
  out[id] = f2bf(th[(i * 64 + o) * 3 + k]);
}

// ---------- prep: Bt[n][k*1024+m] = bf16(Lk[k][n][m]) ----------
__global__ void prep_bt(const float* __restrict__ Lk, ushort_t* __restrict__ Bt) {
  int id = blockIdx.x * 256 + threadIdx.x;          // 393216 chunks of 8
  int k = id >> 17, rem = id & 131071;
  int n = rem >> 7, mc = rem & 127;
  int m = mc << 3;
  const float* src = Lk + ((k * N_ + n) * N_ + m);
  float4 v0 = *(const float4*)src;
  float4 v1 = *(const float4*)(src + 4);
  short8 o8;
  o8[0] = (short)f2bf(v0.x); o8[1] = (short)f2bf(v0.y);
  o8[2] = (short)f2bf(v0.z); o8[3] = (short)f2bf(v0.w);
  o8[4] = (short)f2bf(v1.x); o8[5] = (short)f2bf(v1.y);
  o8[6] = (short)f2bf(v1.z); o8[7] = (short)f2bf(v1.w);
  *(short8*)&Bt[n * KC_ + k * N_ + m] = o8;
}

// ---------- channel mix: Y[(b_l*12+t)*64+o][k*1024+m] = bf16(sum_i th[i,o,k]*in[b,i,t,m]) ----------
template<int IN_BF16>
__global__ __launch_bounds__(256, 2)
void mix_kernel(const void* __restrict__ in, const ushort_t* __restrict__ th,
                ushort_t* __restrict__ Y, int b0) {
  const int bid = blockIdx.x;
  const int b_l = bid / 96, tile = bid % 96;
  const int b = b0 + b_l;
  const int t = tile >> 3, m0 = (tile & 7) << 7;
  const int tid = threadIdx.x;
  __shared__ __align__(16) ushort_t xl[64 * 128];     // bf16 [i][m]   16KB
  __shared__ __align__(16) ushort_t thl[64 * 192];    // bf16 [i][k*64+o] 24KB
  if (IN_BF16) {
    const ushort_t* xg = (const ushort_t*)in;
    #pragma unroll
    for (int j = 0; j < 4; ++j) {
      int c = tid + j * 256;
      int row = c >> 4, col = (c & 15) << 3;
      *(short8*)&xl[row * 128 + col] =
          *(const short8*)&xg[((b * C_ + row) * T_ + t) * N_ + m0 + col];
    }
  } else {
    const float* xg = (const float*)in;
    #pragma unroll
    for (int j = 0; j < 8; ++j) {
      int c = tid + j * 256;
      int row = c >> 5, col = (c & 31) << 2;
      float4 v = *(const float4*)&xg[((b * C_ + row) * T_ + t) * N_ + m0 + col];
      u64 w = (u64)f2bf(v.x) | ((u64)f2bf(v.y) << 16) |
              ((u64)f2bf(v.z) << 32) | ((u64)f2bf(v.w) << 48);
      *(u64*)&xl[row * 128 + col] = w;
    }
  }
  #pragma unroll
  for (int j = 0; j < 6; ++j) {                       // 12288 bf16 theta
    int c = tid + j * 256;
    *(short8*)&thl[c * 8] = *(const short8*)&th[c * 8];
  }
  __syncthreads();
  const int mg = tid & 15, og = tid >> 4;
  float acc[3][4][8] = {};
  #pragma unroll 2
  for (int i = 0; i < 64; ++i) {
    short8 xv = *(const short8*)&xl[i * 128 + mg * 8];
    float xf[8];
    #pragma unroll
    for (int j = 0; j < 8; ++j) xf[j] = bf2f((ushort_t)xv[j]);
    #pragma unroll
    for (int k = 0; k < 3; ++k) {
      u64 tw4 = *(const u64*)&thl[i * 192 + k * 64 + og * 4];
      #pragma unroll
      for (int oo = 0; oo < 4; ++oo) {
        float w = bf2f((ushort_t)(tw4 >> (16 * oo)));
        #pragma unroll
        for (int j = 0; j < 8; ++j) acc[k][oo][j] = fmaf(w, xf[j], acc[k][oo][j]);
      }
    }
  }
  const int rbase = (b_l * T_ + t) * C_;
  #pragma unroll
  for (int k = 0; k < 3; ++k)
    #pragma unroll
    for (int oo = 0; oo < 4; ++oo) {
      int o = og * 4 + oo;
      int r = rbase + o;
      short8 w8;
      #pragma unroll
      for (int j = 0; j < 8; ++j) w8[j] = (short)f2bf(acc[k][oo][j]);
      *(short8*)&Y[r * KC_ + k * N_ + m0 + mg * 8] = w8;
    }
}

// ---------- big GEMM: C = Y @ Bt^T, epilogue bias+residual+relu, bf16 store ----------
template<int RES_BF16>
__global__ __launch_bounds__(256, 2)
void gemm_layer(const ushort_t* __restrict__ Y, const ushort_t* __restrict__ Bt,
                const void* __restrict__ res, const float* __restrict__ bias,
                ushort_t* __restrict__ outb, int b0) {
  const int ntile = blockIdx.x;        // 0..7
  const int mtile = blockIdx.y;
  const int tid = threadIdx.x;
  const int wid = tid >> 6, lane = tid & 63;
  const int wr = wid >> 1, wc = wid & 1;
  __shared__ __align__(16) ushort_t Al[128 * 32];
  __shared__ __align__(16) ushort_t Bl[128 * 32];
  const int row0 = mtile * 128;
  const int n0 = ntile * 128;

  const int c0 = tid;                  // staging chunk id (16B chunks)
  const ushort_t* ga0 = Y  + (row0 + (c0 >> 2)) * KC_ + ((c0 & 3) << 3);
  const ushort_t* ga1 = Y  + (row0 + (c0 >> 2) + 64) * KC_ + ((c0 & 3) << 3);
  const ushort_t* gb0 = Bt + (n0 + (c0 >> 2)) * KC_ + ((c0 & 3) << 3);
  const ushort_t* gb1 = Bt + (n0 + (c0 >> 2) + 64) * KC_ + ((c0 & 3) << 3);
  ushort_t* laA0 = &Al[wid * 512];
  ushort_t* laA1 = &Al[2048 + wid * 512];
  ushort_t* laB0 = &Bl[wid * 512];
  ushort_t* laB1 = &Bl[2048 + wid * 512];

  f32x4 acc[4][4] = {};
  const int l15 = lane & 15, l4 = lane >> 4;
  int aoff[4], boff[4];
  #pragma unroll
  for (int i = 0; i < 4; ++i) {
    aoff[i] = (wr * 64 + i * 16 + l15) * 32 + l4 * 8;
    boff[i] = (wc * 64 + i * 16 + l15) * 32 + l4 * 8;
  }

  for (int kt = 0; kt < KC_ / 32; ++kt) {
    const int ko = kt * 32;
    gload16(ga0 + ko, laA0);
    gload16(ga1 + ko, laA1);
    gload16(gb0 + ko, laB0);
    gload16(gb1 + ko, laB1);
    __syncthreads();
    short8 af[4], bfv[4];
    #pragma unroll
    for (int i = 0; i < 4; ++i) af[i]  = *(const short8*)&Al[aoff[i]];
    #pragma unroll
    for (int i = 0; i < 4; ++i) bfv[i] = *(const short8*)&Bl[boff[i]];
    #pragma unroll
    for (int mi = 0; mi < 4; ++mi)
      #pragma unroll
      for (int ni = 0; ni < 4; ++ni)
        acc[mi][ni] = __builtin_amdgcn_mfma_f32_16x16x32_bf16(af[mi], bfv[ni], acc[mi][ni], 0, 0, 0);
    __syncthreads();
  }

  const float*    resf = (const float*)res;
  const ushort_t* resb = (const ushort_t*)res;
  #pragma unroll
  for (int mi = 0; mi < 4; ++mi) {
    #pragma unroll
    for (int r = 0; r < 4; ++r) {
      int R = row0 + wr * 64 + mi * 16 + l4 * 4 + r;  // chunk-local Y row
      int gb_ = b0 + R / RPB;
      int rem = R % RPB;
      int t = rem >> 6, o = rem & 63;
      float bs = bias[o];
      int base = ((gb_ * C_ + o) * T_ + t) * N_;
      #pragma unroll
      for (int ni = 0; ni < 4; ++ni) {
        int col = n0 + wc * 64 + ni * 16 + l15;
        float rv = RES_BF16 ? bf2f(resb[base + col]) : resf[base + col];
        float v = acc[mi][ni][r] + bs + rv;
        v = fmaxf(v, 0.0f);
        outb[base + col] = f2bf(v);
      }
    }
  }
}

// ---------- FC: out[b,t,n,o2] = sum_o fw[o2,o]*x2[b,o,t,n] + fb[o2] ----------
__global__ __launch_bounds__(256, 2)
void fc_kernel(const ushort_t* __restrict__ x2, const float* __restrict__ fw,
               const float* __restrict__ fb, float* __restrict__ out) {
  int bid = blockIdx.x;                 // 32*12*16
  int nt = bid & 15, btid = bid >> 4;
  int t = btid % 12, b = btid / 12;
  int n0 = nt << 6;
  int tid = threadIdx.x;
  __shared__ float xt[64 * 64];
  __shared__ float wl[64 * 64];
  #pragma unroll
  for (int j = 0; j < 2; ++j) {         // x2 tile: 4096 bf16
    int c = tid + j * 256;
    int row = c >> 3, col = (c & 7) << 3;
    short8 v = *(const short8*)&x2[((b * C_ + row) * T_ + t) * N_ + n0 + col];
    #pragma unroll
    for (int q = 0; q < 8; ++q) xt[row * 64 + col + q] = bf2f((ushort_t)v[q]);
  }
  #pragma unroll
  for (int j = 0; j < 4; ++j) {         // w transpose: wl[o][o2]
    int c = tid + j * 256;
    int o2 = c >> 4, o4 = (c & 15) << 2;
    float4 v = *(const float4*)&fw[o2 * 64 + o4];
    wl[(o4 + 0) * 64 + o2] = v.x; wl[(o4 + 1) * 64 + o2] = v.y;
    wl[(o4 + 2) * 64 + o2] = v.z; wl[(o4 + 3) * 64 + o2] = v.w;
  }
  __syncthreads();
  int p = tid & 31, ng = tid >> 5;      // o2 in {p, p+32}, n = n0+ng*8+j
  float a0[8] = {}, a1[8] = {};
  for (int o = 0; o < 64; ++o) {
    float w0 = wl[o * 64 + p], w1 = wl[o * 64 + p + 32];
    float4 xa = *(const float4*)&xt[o * 64 + ng * 8];
    float4 xb = *(const float4*)&xt[o * 64 + ng * 8 + 4];
    float xv[8] = {xa.x, xa.y, xa.z, xa.w, xb.x, xb.y, xb.z, xb.w};
    #pragma unroll
    for (int j = 0; j < 8; ++j) { a0[j] = fmaf(w0, xv[j], a0[j]); a1[j] = fmaf(w1, xv[j], a1[j]); }
  }
  float fb0 = fb[p], fb1 = fb[p + 32];
  int obase = (b * T_ + t) * N_ + n0 + ng * 8;
  #pragma unroll
  for (int j = 0; j < 8; ++j) {
    out[(obase + j) * 64 + p]      = a0[j] + fb0;
    out[(obase + j) * 64 + p + 32] = a1[j] + fb1;
  }
}

extern "C" void kernel_launch(void* const* d_in, const int* in_sizes, int n_in,
                              void* d_out, int out_size, void* d_ws, size_t ws_size,
                              hipStream_t stream) {
  const float* x   = (const float*)d_in[0];
  const float* Lk  = (const float*)d_in[1];
  const float* th1 = (const float*)d_in[2];
  const float* b1  = (const float*)d_in[3];
  const float* th2 = (const float*)d_in[4];
  const float* b2  = (const float*)d_in[5];
  const float* fcw = (const float*)d_in[6];
  const float* fcb = (const float*)d_in[7];

  char* ws = (char*)d_ws;
  size_t off = 0;
  auto alloc = [&](size_t bytes) { size_t p = off; off += (bytes + 255) & ~(size_t)255; return p; };
  size_t oBt = alloc((size_t)KC_ * N_ * 2);            // 6.29 MB
  size_t oTh = alloc((size_t)2 * 64 * 192 * 2);        // 48 KB
  size_t oX2 = alloc((size_t)B_ * C_ * T_ * N_ * 2);   // 50.3 MB
  size_t perB = (size_t)RPB * KC_ * 2;                 // 4.72 MB per batch of Y
  size_t avail = ws_size > off ? ws_size - off : 0;
  int NB = (int)(avail / perB);
  if (NB > B_) NB = B_;
  if (NB < 1) NB = 1;                                  // (assume ws is big enough)

  ushort_t* Bt = (ushort_t*)(ws + oBt);
  ushort_t* Th = (ushort_t*)(ws + oTh);
  ushort_t* X2 = (ushort_t*)(ws + oX2);
  ushort_t* Yb = (ushort_t*)(ws + off);
  ushort_t* X1 = (ushort_t*)d_out;                     // d_out first half as bf16 scratch

  prep_th<<<96, 256, 0, stream>>>(th1, th2, Th);
  prep_bt<<<1536, 256, 0, stream>>>(Lk, Bt);

  // layer 1: in = x (f32), residual = x (f32), out = X1 (bf16 in d_out)
  for (int b0 = 0; b0 < B_; b0 += NB) {
    int nb = (b0 + NB <= B_) ? NB : (B_ - b0);
    mix_kernel<0><<<nb * 96, 256, 0, stream>>>((const void*)x, Th, Yb, b0);
    gemm_layer<0><<<dim3(8, nb * 6), 256, 0, stream>>>(Yb, Bt, (const void*)x, b1, X1, b0);
  }
  // layer 2: in = X1 (bf16), residual = X1, out = X2 (ws)
  for (int b0 = 0; b0 < B_; b0 += NB) {
    int nb = (b0 + NB <= B_) ? NB : (B_ - b0);
    mix_kernel<1><<<nb * 96, 256, 0, stream>>>((const void*)X1, Th + 12288, Yb, b0);
    gemm_layer<1><<<dim3(8, nb * 6), 256, 0, stream>>>(Yb, Bt, (const void*)X1, b2, X2, b0);
  }
  fc_kernel<<<32 * 12 * 16, 256, 0, stream>>>(X2, fcw, fcb, (float*)d_out);
}

// Round 2
// 683.305 us; speedup vs baseline: 1.1456x; 1.1456x over previous
//
#include <hip/hip_runtime.h>

typedef unsigned short ushort_t;
typedef unsigned long long u64;
typedef short short8 __attribute__((ext_vector_type(8)));
typedef float f32x4 __attribute__((ext_vector_type(4)));

#define B_   32
#define C_   64
#define T_   12
#define N_   1024
#define KS_  3
#define KC_  3072
#define RPB  768
#define NT_  48          // K-tiles of 64

__device__ __forceinline__ float bf2f(ushort_t u) {
  union { unsigned u; float f; } v; v.u = ((unsigned)u) << 16; return v.f;
}
__device__ __forceinline__ ushort_t f2bf(float f) {
  union { float f; unsigned u; } v; v.f = f;
  unsigned r = v.u + 0x7FFFu + ((v.u >> 16) & 1u);
  return (ushort_t)(r >> 16);
}

__device__ __forceinline__ void gload16(const ushort_t* g, ushort_t* l) {
  __builtin_amdgcn_global_load_lds(
      (const __attribute__((address_space(1))) unsigned int*)g,
      (__attribute__((address_space(3))) unsigned int*)l, 16, 0, 0);
}

// ---------- prep: theta pack  thp[l][i][k*64+o] = bf16(theta_l[i][o][k]) ----------
__global__ void prep_th(const float* __restrict__ th1, const float* __restrict__ th2,
                        ushort_t* __restrict__ out) {
  int id = blockIdx.x * 256 + threadIdx.x;          // 2*64*192 = 24576
  if (id >= 2 * 64 * 192) return;
  int l = id / 12288, rem = id % 12288;
  int i = rem / 192, kk = rem % 192;
  int k = kk >> 6, o = kk & 63;
  const float* th = l ? th2 : th1;
  out[id] = f2bf(th[(i * 64 + o) * 3 + k]);
}

// ---------- prep: Bt[n][k*1024+m] = bf16(Lk[k][n][m]) ----------
__global__ void prep_bt(const float* __restrict__ Lk, ushort_t* __restrict__ Bt) {
  int id = blockIdx.x * 256 + threadIdx.x;          // 393216 chunks of 8
  int k = id >> 17, rem = id & 131071;
  int n = rem >> 7, mc = rem & 127;
  int m = mc << 3;
  const float* src = Lk + ((k * N_ + n) * N_ + m);
  float4 v0 = *(const float4*)src;
  float4 v1 = *(const float4*)(src + 4);
  short8 o8;
  o8[0] = (short)f2bf(v0.x); o8[1] = (short)f2bf(v0.y);
  o8[2] = (short)f2bf(v0.z); o8[3] = (short)f2bf(v0.w);
  o8[4] = (short)f2bf(v1.x); o8[5] = (short)f2bf(v1.y);
  o8[6] = (short)f2bf(v1.z); o8[7] = (short)f2bf(v1.w);
  *(short8*)&Bt[n * KC_ + k * N_ + m] = o8;
}

// ---------- channel mix: Y[(b_l*12+t)*64+o][k*1024+m] = bf16(sum_i th[i,o,k]*in[b,i,t,m]) ----------
template<int IN_BF16>
__global__ __launch_bounds__(256, 2)
void mix_kernel(const void* __restrict__ in, const ushort_t* __restrict__ th,
                ushort_t* __restrict__ Y, int b0) {
  const int bid = blockIdx.x;
  const int b_l = bid / 96, tile = bid % 96;
  const int b = b0 + b_l;
  const int t = tile >> 3, m0 = (tile & 7) << 7;
  const int tid = threadIdx.x;
  __shared__ __align__(16) ushort_t xl[64 * 128];
  __shared__ __align__(16) ushort_t thl[64 * 192];
  if (IN_BF16) {
    const ushort_t* xg = (const ushort_t*)in;
    #pragma unroll
    for (int j = 0; j < 4; ++j) {
      int c = tid + j * 256;
      int row = c >> 4, col = (c & 15) << 3;
      *(short8*)&xl[row * 128 + col] =
          *(const short8*)&xg[((b * C_ + row) * T_ + t) * N_ + m0 + col];
    }
  } else {
    const float* xg = (const float*)in;
    #pragma unroll
    for (int j = 0; j < 8; ++j) {
      int c = tid + j * 256;
      int row = c >> 5, col = (c & 31) << 2;
      float4 v = *(const float4*)&xg[((b * C_ + row) * T_ + t) * N_ + m0 + col];
      u64 w = (u64)f2bf(v.x) | ((u64)f2bf(v.y) << 16) |
              ((u64)f2bf(v.z) << 32) | ((u64)f2bf(v.w) << 48);
      *(u64*)&xl[row * 128 + col] = w;
    }
  }
  #pragma unroll
  for (int j = 0; j < 6; ++j) {
    int c = tid + j * 256;
    *(short8*)&thl[c * 8] = *(const short8*)&th[c * 8];
  }
  __syncthreads();
  const int mg = tid & 15, og = tid >> 4;
  float acc[3][4][8] = {};
  #pragma unroll 2
  for (int i = 0; i < 64; ++i) {
    short8 xv = *(const short8*)&xl[i * 128 + mg * 8];
    float xf[8];
    #pragma unroll
    for (int j = 0; j < 8; ++j) xf[j] = bf2f((ushort_t)xv[j]);
    #pragma unroll
    for (int k = 0; k < 3; ++k) {
      u64 tw4 = *(const u64*)&thl[i * 192 + k * 64 + og * 4];
      #pragma unroll
      for (int oo = 0; oo < 4; ++oo) {
        float w = bf2f((ushort_t)(tw4 >> (16 * oo)));
        #pragma unroll
        for (int j = 0; j < 8; ++j) acc[k][oo][j] = fmaf(w, xf[j], acc[k][oo][j]);
      }
    }
  }
  const int rbase = (b_l * T_ + t) * C_;
  #pragma unroll
  for (int k = 0; k < 3; ++k)
    #pragma unroll
    for (int oo = 0; oo < 4; ++oo) {
      int o = og * 4 + oo;
      int r = rbase + o;
      short8 w8;
      #pragma unroll
      for (int j = 0; j < 8; ++j) w8[j] = (short)f2bf(acc[k][oo][j]);
      *(short8*)&Y[r * KC_ + k * N_ + m0 + mg * 8] = w8;
    }
}

// ---------- 256x256-tile 8-phase GEMM: C = Y @ Bt^T, epilogue bias+residual+relu ----------
// LDS layout (128 KiB): [buf(2)][A|B][ksub(2)][row(256)][col(32 bf16)]
//   A base = buf*65536;  B base = buf*65536 + 32768;  plane stride 16384.
// Swizzle: stored_byte = logical_byte ^ (((logical_byte>>9)&1)<<5)  (involution,
// applied via pre-swizzled GLOBAL source on the write side, XOR on the read side).

#define MFMA16(q)                                                                          \
  acc[2*(q)][0]   = __builtin_amdgcn_mfma_f32_16x16x32_bf16(a00, bf00, acc[2*(q)][0],0,0,0);   \
  acc[2*(q)][0]   = __builtin_amdgcn_mfma_f32_16x16x32_bf16(a01, bf01, acc[2*(q)][0],0,0,0);   \
  acc[2*(q)][1]   = __builtin_amdgcn_mfma_f32_16x16x32_bf16(a00, bf10, acc[2*(q)][1],0,0,0);   \
  acc[2*(q)][1]   = __builtin_amdgcn_mfma_f32_16x16x32_bf16(a01, bf11, acc[2*(q)][1],0,0,0);   \
  acc[2*(q)][2]   = __builtin_amdgcn_mfma_f32_16x16x32_bf16(a00, bf20, acc[2*(q)][2],0,0,0);   \
  acc[2*(q)][2]   = __builtin_amdgcn_mfma_f32_16x16x32_bf16(a01, bf21, acc[2*(q)][2],0,0,0);   \
  acc[2*(q)][3]   = __builtin_amdgcn_mfma_f32_16x16x32_bf16(a00, bf30, acc[2*(q)][3],0,0,0);   \
  acc[2*(q)][3]   = __builtin_amdgcn_mfma_f32_16x16x32_bf16(a01, bf31, acc[2*(q)][3],0,0,0);   \
  acc[2*(q)+1][0] = __builtin_amdgcn_mfma_f32_16x16x32_bf16(a10, bf00, acc[2*(q)+1][0],0,0,0); \
  acc[2*(q)+1][0] = __builtin_amdgcn_mfma_f32_16x16x32_bf16(a11, bf01, acc[2*(q)+1][0],0,0,0); \
  acc[2*(q)+1][1] = __builtin_amdgcn_mfma_f32_16x16x32_bf16(a10, bf10, acc[2*(q)+1][1],0,0,0); \
  acc[2*(q)+1][1] = __builtin_amdgcn_mfma_f32_16x16x32_bf16(a11, bf11, acc[2*(q)+1][1],0,0,0); \
  acc[2*(q)+1][2] = __builtin_amdgcn_mfma_f32_16x16x32_bf16(a10, bf20, acc[2*(q)+1][2],0,0,0); \
  acc[2*(q)+1][2] = __builtin_amdgcn_mfma_f32_16x16x32_bf16(a11, bf21, acc[2*(q)+1][2],0,0,0); \
  acc[2*(q)+1][3] = __builtin_amdgcn_mfma_f32_16x16x32_bf16(a10, bf30, acc[2*(q)+1][3],0,0,0); \
  acc[2*(q)+1][3] = __builtin_amdgcn_mfma_f32_16x16x32_bf16(a11, bf31, acc[2*(q)+1][3],0,0,0);

#define STAGE_A(kt, h) do {                                                   \
    const ushort_t* g_ = gA + (size_t)(h) * 128 * KC_ + (size_t)(kt) * 64;    \
    char* d_ = lp + (((kt) & 1) << 16) + (h) * 8192 + w1024;                  \
    gload16(g_, (ushort_t*)d_);                                               \
    gload16(g_ + 32, (ushort_t*)(d_ + 16384));                                \
  } while (0)

#define STAGE_B(kt, h) do {                                                   \
    const ushort_t* g_ = gB + (size_t)(h) * 128 * KC_ + (size_t)(kt) * 64;    \
    char* d_ = lp + (((kt) & 1) << 16) + 32768 + (h) * 8192 + w1024;          \
    gload16(g_, (ushort_t*)d_);                                               \
    gload16(g_ + 32, (ushort_t*)(d_ + 16384));                                \
  } while (0)

template<int RES_BF16>
__global__ __launch_bounds__(512, 2)
void gemm8p(const ushort_t* __restrict__ Y, const ushort_t* __restrict__ Bt,
            const void* __restrict__ res, const float* __restrict__ bias,
            ushort_t* __restrict__ outb, int b0) {
  // bijective XCD swizzle (m204): consecutive wg within an XCD chunk share mtile
  const int nwg = gridDim.x;
  int orig = blockIdx.x;
  int q8 = nwg >> 3, r8 = nwg & 7;
  int xcd = orig & 7, idx = orig >> 3;
  int wg = (xcd < r8 ? xcd * (q8 + 1) : r8 * (q8 + 1) + (xcd - r8) * q8) + idx;
  const int mtile = wg >> 2, ntile = wg & 3;

  const int tid = threadIdx.x;
  const int wid = tid >> 6, lane = tid & 63;
  const int wm = wid >> 2, wn = wid & 3;
  const int l15 = lane & 15, l4 = lane >> 4;

  __shared__ ushort_t LDSU[65536];   // 128 KiB
  char* lp = (char*)LDSU;

  // read-side lane byte offsets (swizzle: XOR bit5 when (row>>3)&1; row low bits = l15)
  const int swz_r = ((l15 >> 3) & 1) << 5;
  const int a_lo = wm * 1024 + l15 * 64 + ((l4 * 16) ^ swz_r);
  const int b_lo = wn * 1024 + l15 * 64 + ((l4 * 16) ^ swz_r);

  // staging: LDS dest linear (wave-uniform base + lane*16); global col pre-swizzled
  const int g_col = ((lane & 3) * 8) ^ ((lane >> 5) << 4);
  const int g_row = wid * 16 + (lane >> 2);
  const ushort_t* gA = Y  + (size_t)(mtile * 256 + g_row) * KC_ + g_col;
  const ushort_t* gB = Bt + (size_t)(ntile * 256 + g_row) * KC_ + g_col;
  const int w1024 = wid * 1024;

  // prologue: 7 half-tiles (K-tile 0 complete + 3 of K-tile 1)
  STAGE_B(0, 0); STAGE_B(0, 1); STAGE_A(0, 0); STAGE_A(0, 1);
  STAGE_B(1, 0); STAGE_B(1, 1); STAGE_A(1, 0);
  asm volatile("s_waitcnt vmcnt(6)" ::: "memory");   // K-tile 0 landed
  __builtin_amdgcn_s_barrier();

  f32x4 acc[8][4] = {};

  for (int u = 0; u < NT_; ++u) {
    const char* ab = lp + ((u & 1) << 16) + a_lo;
    const char* bb = lp + ((u & 1) << 16) + 32768 + b_lo;

    // B fragments for the whole K-tile (8 x ds_read_b128), held in regs
    short8 bf00 = *(const short8*)(bb);
    short8 bf01 = *(const short8*)(bb + 16384);
    short8 bf10 = *(const short8*)(bb + 4096);
    short8 bf11 = *(const short8*)(bb + 4096 + 16384);
    short8 bf20 = *(const short8*)(bb + 8192);
    short8 bf21 = *(const short8*)(bb + 8192 + 16384);
    short8 bf30 = *(const short8*)(bb + 12288);
    short8 bf31 = *(const short8*)(bb + 12288 + 16384);

    { // phase 0: mf 0,1 ; stage Ah1(u+1) -> other buf (region dead since prev phase)
      short8 a00 = *(const short8*)(ab);
      short8 a01 = *(const short8*)(ab + 16384);
      short8 a10 = *(const short8*)(ab + 2048);
      short8 a11 = *(const short8*)(ab + 2048 + 16384);
      if (u + 1 < NT_) STAGE_A(u + 1, 1);
      __builtin_amdgcn_s_barrier();
      __builtin_amdgcn_s_setprio(1);
      MFMA16(0)
      __builtin_amdgcn_s_setprio(0);
      __builtin_amdgcn_s_barrier();
    }
    { // phase 1: mf 2,3 ; stage Bh0(u+2) (B of u fully read in phase 0)
      short8 a00 = *(const short8*)(ab + 2 * 2048);
      short8 a01 = *(const short8*)(ab + 2 * 2048 + 16384);
      short8 a10 = *(const short8*)(ab + 3 * 2048);
      short8 a11 = *(const short8*)(ab + 3 * 2048 + 16384);
      if (u + 2 < NT_) STAGE_B(u + 2, 0);
      __builtin_amdgcn_s_barrier();
      __builtin_amdgcn_s_setprio(1);
      MFMA16(1)
      __builtin_amdgcn_s_setprio(0);
      __builtin_amdgcn_s_barrier();
    }
    { // phase 2: mf 4,5 ; stage Bh1(u+2)
      short8 a00 = *(const short8*)(ab + 4 * 2048);
      short8 a01 = *(const short8*)(ab + 4 * 2048 + 16384);
      short8 a10 = *(const short8*)(ab + 5 * 2048);
      short8 a11 = *(const short8*)(ab + 5 * 2048 + 16384);
      if (u + 2 < NT_) STAGE_B(u + 2, 1);
      __builtin_amdgcn_s_barrier();
      __builtin_amdgcn_s_setprio(1);
      MFMA16(2)
      __builtin_amdgcn_s_setprio(0);
      __builtin_amdgcn_s_barrier();
    }
    { // phase 3: mf 6,7 ; stage Ah0(u+2) (rows 0-127 of u last read in phase 1)
      short8 a00 = *(const short8*)(ab + 6 * 2048);
      short8 a01 = *(const short8*)(ab + 6 * 2048 + 16384);
      short8 a10 = *(const short8*)(ab + 7 * 2048);
      short8 a11 = *(const short8*)(ab + 7 * 2048 + 16384);
      if (u + 2 < NT_) {
        STAGE_A(u + 2, 0);
        asm volatile("s_waitcnt vmcnt(6)" ::: "memory");  // K-tile u+1 complete
      } else if (u + 2 == NT_) {
        asm volatile("s_waitcnt vmcnt(0)" ::: "memory");  // drain for last K-tile
      }
      __builtin_amdgcn_s_barrier();
      __builtin_amdgcn_s_setprio(1);
      MFMA16(3)
      __builtin_amdgcn_s_setprio(0);
      __builtin_amdgcn_s_barrier();
    }
  }

  // epilogue: bias + residual + relu, bf16 store
  const float*    resf = (const float*)res;
  const ushort_t* resb = (const ushort_t*)res;
  const int mt3 = mtile % 3;
  const int gb = b0 + mtile / 3;
  const int colb = ntile * 256 + wn * 16 + l15;
  #pragma unroll
  for (int mf = 0; mf < 8; ++mf) {
    #pragma unroll
    for (int r = 0; r < 4; ++r) {
      int rl = mf * 32 + wm * 16 + l4 * 4 + r;
      int rem = mt3 * 256 + rl;
      int t = rem >> 6, o = rem & 63;
      float bs = bias[o];
      size_t base = ((size_t)(gb * C_ + o) * T_ + t) * N_;
      #pragma unroll
      for (int nf = 0; nf < 4; ++nf) {
        int col = colb + nf * 64;
        float rv = RES_BF16 ? bf2f(resb[base + col]) : resf[base + col];
        float v = acc[mf][nf][r] + bs + rv;
        v = fmaxf(v, 0.0f);
        outb[base + col] = f2bf(v);
      }
    }
  }
}

// ---------- FC: out[b,t,n,o2] = sum_o fw[o2,o]*x2[b,o,t,n] + fb[o2] ----------
__global__ __launch_bounds__(256, 2)
void fc_kernel(const ushort_t* __restrict__ x2, const float* __restrict__ fw,
               const float* __restrict__ fb, float* __restrict__ out) {
  int bid = blockIdx.x;                 // 32*12*16
  int nt = bid & 15, btid = bid >> 4;
  int t = btid % 12, b = btid / 12;
  int n0 = nt << 6;
  int tid = threadIdx.x;
  __shared__ float xt[64 * 64];
  __shared__ float wl[64 * 64];
  #pragma unroll
  for (int j = 0; j < 2; ++j) {
    int c = tid + j * 256;
    int row = c >> 3, col = (c & 7) << 3;
    short8 v = *(const short8*)&x2[((b * C_ + row) * T_ + t) * N_ + n0 + col];
    #pragma unroll
    for (int q = 0; q < 8; ++q) xt[row * 64 + col + q] = bf2f((ushort_t)v[q]);
  }
  #pragma unroll
  for (int j = 0; j < 4; ++j) {
    int c = tid + j * 256;
    int o2 = c >> 4, o4 = (c & 15) << 2;
    float4 v = *(const float4*)&fw[o2 * 64 + o4];
    wl[(o4 + 0) * 64 + o2] = v.x; wl[(o4 + 1) * 64 + o2] = v.y;
    wl[(o4 + 2) * 64 + o2] = v.z; wl[(o4 + 3) * 64 + o2] = v.w;
  }
  __syncthreads();
  int p = tid & 31, ng = tid >> 5;
  float a0[8] = {}, a1[8] = {};
  for (int o = 0; o < 64; ++o) {
    float w0 = wl[o * 64 + p], w1 = wl[o * 64 + p + 32];
    float4 xa = *(const float4*)&xt[o * 64 + ng * 8];
    float4 xb = *(const float4*)&xt[o * 64 + ng * 8 + 4];
    float xv[8] = {xa.x, xa.y, xa.z, xa.w, xb.x, xb.y, xb.z, xb.w};
    #pragma unroll
    for (int j = 0; j < 8; ++j) { a0[j] = fmaf(w0, xv[j], a0[j]); a1[j] = fmaf(w1, xv[j], a1[j]); }
  }
  float fb0 = fb[p], fb1 = fb[p + 32];
  int obase = (b * T_ + t) * N_ + n0 + ng * 8;
  #pragma unroll
  for (int j = 0; j < 8; ++j) {
    out[(obase + j) * 64 + p]      = a0[j] + fb0;
    out[(obase + j) * 64 + p + 32] = a1[j] + fb1;
  }
}

extern "C" void kernel_launch(void* const* d_in, const int* in_sizes, int n_in,
                              void* d_out, int out_size, void* d_ws, size_t ws_size,
                              hipStream_t stream) {
  const float* x   = (const float*)d_in[0];
  const float* Lk  = (const float*)d_in[1];
  const float* th1 = (const float*)d_in[2];
  const float* b1  = (const float*)d_in[3];
  const float* th2 = (const float*)d_in[4];
  const float* b2  = (const float*)d_in[5];
  const float* fcw = (const float*)d_in[6];
  const float* fcb = (const float*)d_in[7];

  char* ws = (char*)d_ws;
  size_t off = 0;
  auto alloc = [&](size_t bytes) { size_t p = off; off += (bytes + 255) & ~(size_t)255; return p; };
  size_t oBt = alloc((size_t)KC_ * N_ * 2);            // 6.29 MB
  size_t oTh = alloc((size_t)2 * 64 * 192 * 2);        // 48 KB
  size_t oX2 = alloc((size_t)B_ * C_ * T_ * N_ * 2);   // 50.3 MB
  size_t perB = (size_t)RPB * KC_ * 2;                 // 4.72 MB per batch of Y
  size_t avail = ws_size > off ? ws_size - off : 0;
  int NB = (int)(avail / perB);
  if (NB > B_) NB = B_;
  if (NB < 1) NB = 1;

  ushort_t* Bt = (ushort_t*)(ws + oBt);
  ushort_t* Th = (ushort_t*)(ws + oTh);
  ushort_t* X2 = (ushort_t*)(ws + oX2);
  ushort_t* Yb = (ushort_t*)(ws + off);
  ushort_t* X1 = (ushort_t*)d_out;                     // d_out as bf16 scratch until FC

  prep_th<<<96, 256, 0, stream>>>(th1, th2, Th);
  prep_bt<<<1536, 256, 0, stream>>>(Lk, Bt);

  // layer 1: in = x (f32), residual = x (f32), out = X1 (bf16 in d_out)
  for (int b0 = 0; b0 < B_; b0 += NB) {
    int nb = (b0 + NB <= B_) ? NB : (B_ - b0);
    mix_kernel<0><<<nb * 96, 256, 0, stream>>>((const void*)x, Th, Yb, b0);
    gemm8p<0><<<dim3(12 * nb), 512, 0, stream>>>(Yb, Bt, (const void*)x, b1, X1, b0);
  }
  // layer 2: in = X1 (bf16), residual = X1, out = X2 (ws)
  for (int b0 = 0; b0 < B_; b0 += NB) {
    int nb = (b0 + NB <= B_) ? NB : (B_ - b0);
    mix_kernel<1><<<nb * 96, 256, 0, stream>>>((const void*)X1, Th + 12288, Yb, b0);
    gemm8p<1><<<dim3(12 * nb), 512, 0, stream>>>(Yb, Bt, (const void*)X1, b2, X2, b0);
  }
  fc_kernel<<<32 * 12 * 16, 256, 0, stream>>>(X2, fcw, fcb, (float*)d_out);
}

// Round 4
// 653.509 us; speedup vs baseline: 1.1979x; 1.0456x over previous
//
#include <hip/hip_runtime.h>

typedef unsigned short ushort_t;
typedef unsigned long long u64;
typedef short short8 __attribute__((ext_vector_type(8)));
typedef float f32x4 __attribute__((ext_vector_type(4)));

#define B_   32
#define C_   64
#define T_   12
#define N_   1024
#define KS_  3
#define KC_  3072
#define RPB  768
#define NT_  48          // K-tiles of 64
#define BM_  192
#define LBUF 57344       // bytes per LDS buffer: A 192*64*2 (=24576) + B 256*64*2 (=32768)
#define ABYT 24576       // A region bytes (plane stride 12288)
#define BPLN 16384       // B plane stride

__device__ __forceinline__ float bf2f(ushort_t u) {
  union { unsigned u; float f; } v; v.u = ((unsigned)u) << 16; return v.f;
}
__device__ __forceinline__ ushort_t f2bf(float f) {
  union { float f; unsigned u; } v; v.f = f;
  unsigned r = v.u + 0x7FFFu + ((v.u >> 16) & 1u);
  return (ushort_t)(r >> 16);
}

__device__ __forceinline__ void gload16(const ushort_t* g, ushort_t* l) {
  __builtin_amdgcn_global_load_lds(
      (const __attribute__((address_space(1))) unsigned int*)g,
      (__attribute__((address_space(3))) unsigned int*)l, 16, 0, 0);
}

// ---------- prep: theta pack  thp[l][i][k*64+o] = bf16(theta_l[i][o][k]) ----------
__global__ void prep_th(const float* __restrict__ th1, const float* __restrict__ th2,
                        ushort_t* __restrict__ out) {
  int id = blockIdx.x * 256 + threadIdx.x;
  if (id >= 2 * 64 * 192) return;
  int l = id / 12288, rem = id % 12288;
  int i = rem / 192, kk = rem % 192;
  int k = kk >> 6, o = kk & 63;
  const float* th = l ? th2 : th1;
  out[id] = f2bf(th[(i * 64 + o) * 3 + k]);
}

// ---------- prep: Bt[n][k*1024+m] = bf16(Lk[k][n][m]) ----------
__global__ void prep_bt(const float* __restrict__ Lk, ushort_t* __restrict__ Bt) {
  int id = blockIdx.x * 256 + threadIdx.x;
  int k = id >> 17, rem = id & 131071;
  int n = rem >> 7, mc = rem & 127;
  int m = mc << 3;
  const float* src = Lk + ((k * N_ + n) * N_ + m);
  float4 v0 = *(const float4*)src;
  float4 v1 = *(const float4*)(src + 4);
  short8 o8;
  o8[0] = (short)f2bf(v0.x); o8[1] = (short)f2bf(v0.y);
  o8[2] = (short)f2bf(v0.z); o8[3] = (short)f2bf(v0.w);
  o8[4] = (short)f2bf(v1.x); o8[5] = (short)f2bf(v1.y);
  o8[6] = (short)f2bf(v1.z); o8[7] = (short)f2bf(v1.w);
  *(short8*)&Bt[n * KC_ + k * N_ + m] = o8;
}

// ---------- channel mix: Y[(b_l*12+t)*64+o][k*1024+m] = bf16(sum_i th[i,o,k]*in[b,i,t,m]) ----------
template<int IN_BF16>
__global__ __launch_bounds__(256, 2)
void mix_kernel(const void* __restrict__ in, const ushort_t* __restrict__ th,
                ushort_t* __restrict__ Y, int b0) {
  const int bid = blockIdx.x;
  const int b_l = bid / 96, tile = bid % 96;
  const int b = b0 + b_l;
  const int t = tile >> 3, m0 = (tile & 7) << 7;
  const int tid = threadIdx.x;
  __shared__ __align__(16) ushort_t xl[64 * 128];
  __shared__ __align__(16) ushort_t thl[64 * 192];
  if (IN_BF16) {
    const ushort_t* xg = (const ushort_t*)in;
    #pragma unroll
    for (int j = 0; j < 4; ++j) {
      int c = tid + j * 256;
      int row = c >> 4, col = (c & 15) << 3;
      *(short8*)&xl[row * 128 + col] =
          *(const short8*)&xg[((b * C_ + row) * T_ + t) * N_ + m0 + col];
    }
  } else {
    const float* xg = (const float*)in;
    #pragma unroll
    for (int j = 0; j < 8; ++j) {
      int c = tid + j * 256;
      int row = c >> 5, col = (c & 31) << 2;
      float4 v = *(const float4*)&xg[((b * C_ + row) * T_ + t) * N_ + m0 + col];
      u64 w = (u64)f2bf(v.x) | ((u64)f2bf(v.y) << 16) |
              ((u64)f2bf(v.z) << 32) | ((u64)f2bf(v.w) << 48);
      *(u64*)&xl[row * 128 + col] = w;
    }
  }
  #pragma unroll
  for (int j = 0; j < 6; ++j) {
    int c = tid + j * 256;
    *(short8*)&thl[c * 8] = *(const short8*)&th[c * 8];
  }
  __syncthreads();
  const int mg = tid & 15, og = tid >> 4;
  float acc[3][4][8] = {};
  #pragma unroll 2
  for (int i = 0; i < 64; ++i) {
    short8 xv = *(const short8*)&xl[i * 128 + mg * 8];
    float xf[8];
    #pragma unroll
    for (int j = 0; j < 8; ++j) xf[j] = bf2f((ushort_t)xv[j]);
    #pragma unroll
    for (int k = 0; k < 3; ++k) {
      u64 tw4 = *(const u64*)&thl[i * 192 + k * 64 + og * 4];
      #pragma unroll
      for (int oo = 0; oo < 4; ++oo) {
        float w = bf2f((ushort_t)(tw4 >> (16 * oo)));
        #pragma unroll
        for (int j = 0; j < 8; ++j) acc[k][oo][j] = fmaf(w, xf[j], acc[k][oo][j]);
      }
    }
  }
  const int rbase = (b_l * T_ + t) * C_;
  #pragma unroll
  for (int k = 0; k < 3; ++k)
    #pragma unroll
    for (int oo = 0; oo < 4; ++oo) {
      int o = og * 4 + oo;
      int r = rbase + o;
      short8 w8;
      #pragma unroll
      for (int j = 0; j < 8; ++j) w8[j] = (short)f2bf(acc[k][oo][j]);
      *(short8*)&Y[r * KC_ + k * N_ + m0 + mg * 8] = w8;
    }
}

// ---------- 192x256-tile phased GEMM: C = Y @ Bt^T, epilogue bias+residual+relu ----------
// LDS per buffer: A [s:2][row:192][64B] (24576 B) then B [s:2][row:256][64B] (32768 B).
// Swizzle: stored col-byte = logical ^ (((row>>3)&1)<<5); applied on global source
// (write side, since global_load_lds dest must be linear) and on ds_read address.
// FIX vs r2: B-fragment read rows = wn*16 + nf*64 + l15 (frag stride 4096 B), matching
// the epilogue column mapping col = n0 + wn*16 + nf*64 + l15. r2 read wn*64 + nf*16.

#define MFMA12(g)                                                                           \
  acc[3*(g)+0][0] = __builtin_amdgcn_mfma_f32_16x16x32_bf16(a0, b0, acc[3*(g)+0][0],0,0,0); \
  acc[3*(g)+0][1] = __builtin_amdgcn_mfma_f32_16x16x32_bf16(a0, b1, acc[3*(g)+0][1],0,0,0); \
  acc[3*(g)+0][2] = __builtin_amdgcn_mfma_f32_16x16x32_bf16(a0, b2, acc[3*(g)+0][2],0,0,0); \
  acc[3*(g)+0][3] = __builtin_amdgcn_mfma_f32_16x16x32_bf16(a0, b3, acc[3*(g)+0][3],0,0,0); \
  acc[3*(g)+1][0] = __builtin_amdgcn_mfma_f32_16x16x32_bf16(a1, b0, acc[3*(g)+1][0],0,0,0); \
  acc[3*(g)+1][1] = __builtin_amdgcn_mfma_f32_16x16x32_bf16(a1, b1, acc[3*(g)+1][1],0,0,0); \
  acc[3*(g)+1][2] = __builtin_amdgcn_mfma_f32_16x16x32_bf16(a1, b2, acc[3*(g)+1][2],0,0,0); \
  acc[3*(g)+1][3] = __builtin_amdgcn_mfma_f32_16x16x32_bf16(a1, b3, acc[3*(g)+1][3],0,0,0); \
  acc[3*(g)+2][0] = __builtin_amdgcn_mfma_f32_16x16x32_bf16(a2, b0, acc[3*(g)+2][0],0,0,0); \
  acc[3*(g)+2][1] = __builtin_amdgcn_mfma_f32_16x16x32_bf16(a2, b1, acc[3*(g)+2][1],0,0,0); \
  acc[3*(g)+2][2] = __builtin_amdgcn_mfma_f32_16x16x32_bf16(a2, b2, acc[3*(g)+2][2],0,0,0); \
  acc[3*(g)+2][3] = __builtin_amdgcn_mfma_f32_16x16x32_bf16(a2, b3, acc[3*(g)+2][3],0,0,0);

#define STAGE_A(kt, j) gload16(gA##j + (size_t)(kt) * 64,                                   \
    (ushort_t*)(lp + (((kt) & 1) ? LBUF : 0) + (j) * 8192 + wofs))
#define STAGE_B(kt, j) gload16(gB##j + (size_t)(kt) * 64,                                   \
    (ushort_t*)(lp + (((kt) & 1) ? LBUF : 0) + ABYT + (j) * 8192 + wofs))

#define LD8(p) (*(const short8*)(p))

template<int RES_BF16>
__global__ __launch_bounds__(512, 2)
void gemm8p(const ushort_t* __restrict__ Y, const ushort_t* __restrict__ Bt,
            const void* __restrict__ res, const float* __restrict__ bias,
            ushort_t* __restrict__ outb, int batch0) {
  // bijective XCD swizzle; gridDim.x = 16*nb is always a multiple of 8
  const int nwg = gridDim.x;
  int orig = blockIdx.x;
  int q8 = nwg >> 3;
  int wg = (orig & 7) * q8 + (orig >> 3);
  const int mtile = wg >> 2, ntile = wg & 3;

  const int tid = threadIdx.x;
  const int wid = tid >> 6, lane = tid & 63;
  const int wm = wid >> 2, wn = wid & 3;
  const int l15 = lane & 15, l4 = lane >> 4;

  __shared__ ushort_t LDSU[LBUF];   // 114688 bytes total (2 buffers)
  char* lp = (char*)LDSU;

  const int row0 = mtile * BM_;
  const int n0 = ntile * 256;
  const int wofs = wid * 1024;

  // staging source pointers (per-lane, swizzle pre-applied on global col)
  const int lam = lane >> 2, lc = lane & 3;
  const ushort_t *gA0, *gA1, *gA2, *gB0, *gB1, *gB2, *gB3;
  {
    int p, s, row, colel;
    p = 0 * 128 + wid * 16 + lam; s = p >= 192 ? 1 : 0; row = p - s * 192;
    colel = (lc * 8) ^ (((row >> 3) & 1) << 4);
    gA0 = Y + (size_t)(row0 + row) * KC_ + s * 32 + colel;
    p = 1 * 128 + wid * 16 + lam; s = p >= 192 ? 1 : 0; row = p - s * 192;
    colel = (lc * 8) ^ (((row >> 3) & 1) << 4);
    gA1 = Y + (size_t)(row0 + row) * KC_ + s * 32 + colel;
    p = 2 * 128 + wid * 16 + lam; s = p >= 192 ? 1 : 0; row = p - s * 192;
    colel = (lc * 8) ^ (((row >> 3) & 1) << 4);
    gA2 = Y + (size_t)(row0 + row) * KC_ + s * 32 + colel;
    p = 0 * 128 + wid * 16 + lam; s = p >> 8; row = p & 255;
    colel = (lc * 8) ^ (((row >> 3) & 1) << 4);
    gB0 = Bt + (size_t)(n0 + row) * KC_ + s * 32 + colel;
    p = 1 * 128 + wid * 16 + lam; s = p >> 8; row = p & 255;
    colel = (lc * 8) ^ (((row >> 3) & 1) << 4);
    gB1 = Bt + (size_t)(n0 + row) * KC_ + s * 32 + colel;
    p = 2 * 128 + wid * 16 + lam; s = p >> 8; row = p & 255;
    colel = (lc * 8) ^ (((row >> 3) & 1) << 4);
    gB2 = Bt + (size_t)(n0 + row) * KC_ + s * 32 + colel;
    p = 3 * 128 + wid * 16 + lam; s = p >> 8; row = p & 255;
    colel = (lc * 8) ^ (((row >> 3) & 1) << 4);
    gB3 = Bt + (size_t)(n0 + row) * KC_ + s * 32 + colel;
  }

  // read-side lane byte bases (swizzle XOR on col)
  const int swz = ((l15 >> 3) & 1) << 5;
  const int a_base = (wm * 16 + l15) * 64 + ((l4 * 16) ^ swz);
  const int b_base = ABYT + (wn * 16 + l15) * 64 + ((l4 * 16) ^ swz);   // FIXED

  // prologue: tile0 fully, tile1 minus A2
  STAGE_B(0, 0); STAGE_B(0, 1); STAGE_B(0, 2); STAGE_B(0, 3);
  STAGE_A(0, 0); STAGE_A(0, 1); STAGE_A(0, 2);
  STAGE_B(1, 0); STAGE_B(1, 1); STAGE_B(1, 2); STAGE_B(1, 3);
  STAGE_A(1, 0); STAGE_A(1, 1);
  asm volatile("s_waitcnt vmcnt(6)" ::: "memory");   // tile 0 landed
  __builtin_amdgcn_s_barrier();

  f32x4 acc[6][4] = {};
  short8 b0, b1, b2, b3;

  for (int u = 0; u < NT_; ++u) {
    const char* abp = lp + ((u & 1) ? LBUF : 0) + a_base;
    const char* bbp = lp + ((u & 1) ? LBUF : 0) + b_base;

    { // phase 0: (s=0, mf 0-2); stage A2(u+1) [its region sealed at ph3(u-1)]
      short8 a0 = LD8(abp);
      short8 a1 = LD8(abp + 2048);
      short8 a2 = LD8(abp + 4096);
      b0 = LD8(bbp);  b1 = LD8(bbp + 4096);  b2 = LD8(bbp + 8192);  b3 = LD8(bbp + 12288);
      if (u + 1 < NT_) STAGE_A(u + 1, 2);
      __builtin_amdgcn_s_barrier();
      __builtin_amdgcn_s_setprio(1);
      MFMA12(0)
      __builtin_amdgcn_s_setprio(0);
      __builtin_amdgcn_s_barrier();
    }
    { // phase 1: (s=0, mf 3-5); stage B0,B1(u+2) [B s0 sealed after ph0]
      short8 a0 = LD8(abp + 6144);
      short8 a1 = LD8(abp + 8192);
      short8 a2 = LD8(abp + 10240);
      if (u + 2 < NT_) { STAGE_B(u + 2, 0); STAGE_B(u + 2, 1); }
      __builtin_amdgcn_s_barrier();
      __builtin_amdgcn_s_setprio(1);
      MFMA12(1)
      __builtin_amdgcn_s_setprio(0);
      __builtin_amdgcn_s_barrier();
    }
    { // phase 2: (s=1, mf 0-2); no staging
      short8 a0 = LD8(abp + 12288);
      short8 a1 = LD8(abp + 12288 + 2048);
      short8 a2 = LD8(abp + 12288 + 4096);
      b0 = LD8(bbp + BPLN);  b1 = LD8(bbp + BPLN + 4096);
      b2 = LD8(bbp + BPLN + 8192);  b3 = LD8(bbp + BPLN + 12288);
      __builtin_amdgcn_s_barrier();
      __builtin_amdgcn_s_setprio(1);
      MFMA12(0)
      __builtin_amdgcn_s_setprio(0);
      __builtin_amdgcn_s_barrier();
    }
    { // phase 3: (s=1, mf 3-5); stage B2,B3,A0,A1(u+2); counted vmcnt
      short8 a0 = LD8(abp + 12288 + 6144);
      short8 a1 = LD8(abp + 12288 + 8192);
      short8 a2 = LD8(abp + 12288 + 10240);
      if (u + 2 < NT_) {
        STAGE_B(u + 2, 2); STAGE_B(u + 2, 3);
        STAGE_A(u + 2, 0); STAGE_A(u + 2, 1);
        asm volatile("s_waitcnt vmcnt(6)" ::: "memory");  // tile u+1 complete
      } else if (u + 2 == NT_) {
        asm volatile("s_waitcnt vmcnt(0)" ::: "memory");  // drain for last tile
      }
      __builtin_amdgcn_s_barrier();
      __builtin_amdgcn_s_setprio(1);
      MFMA12(1)
      __builtin_amdgcn_s_setprio(0);
      __builtin_amdgcn_s_barrier();
    }
  }

  // epilogue: bias + residual + relu, bf16 store
  const float*    resf = (const float*)res;
  const ushort_t* resb = (const ushort_t*)res;
  const int gb = batch0 + (mtile >> 2);
  const int rowb0 = (mtile & 3) * BM_;
  const int colb = n0 + wn * 16 + l15;
  #pragma unroll
  for (int mf = 0; mf < 6; ++mf) {
    #pragma unroll
    for (int r = 0; r < 4; ++r) {
      int rl = mf * 32 + wm * 16 + l4 * 4 + r;
      int rowb = rowb0 + rl;
      int t = rowb >> 6, o = rowb & 63;
      float bs = bias[o];
      size_t base = ((size_t)(gb * C_ + o) * T_ + t) * N_;
      #pragma unroll
      for (int nf = 0; nf < 4; ++nf) {
        int col = colb + nf * 64;
        float rv = RES_BF16 ? bf2f(resb[base + col]) : resf[base + col];
        float v = acc[mf][nf][r] + bs + rv;
        v = fmaxf(v, 0.0f);
        outb[base + col] = f2bf(v);
      }
    }
  }
}

// ---------- FC: out[b,t,n,o2] = sum_o fw[o2,o]*x2[b,o,t,n] + fb[o2] ----------
__global__ __launch_bounds__(256, 2)
void fc_kernel(const ushort_t* __restrict__ x2, const float* __restrict__ fw,
               const float* __restrict__ fb, float* __restrict__ out) {
  int bid = blockIdx.x;
  int nt = bid & 15, btid = bid >> 4;
  int t = btid % 12, b = btid / 12;
  int n0 = nt << 6;
  int tid = threadIdx.x;
  __shared__ float xt[64 * 64];
  __shared__ float wl[64 * 64];
  #pragma unroll
  for (int j = 0; j < 2; ++j) {
    int c = tid + j * 256;
    int row = c >> 3, col = (c & 7) << 3;
    short8 v = *(const short8*)&x2[((b * C_ + row) * T_ + t) * N_ + n0 + col];
    #pragma unroll
    for (int q = 0; q < 8; ++q) xt[row * 64 + col + q] = bf2f((ushort_t)v[q]);
  }
  #pragma unroll
  for (int j = 0; j < 4; ++j) {
    int c = tid + j * 256;
    int o2 = c >> 4, o4 = (c & 15) << 2;
    float4 v = *(const float4*)&fw[o2 * 64 + o4];
    wl[(o4 + 0) * 64 + o2] = v.x; wl[(o4 + 1) * 64 + o2] = v.y;
    wl[(o4 + 2) * 64 + o2] = v.z; wl[(o4 + 3) * 64 + o2] = v.w;
  }
  __syncthreads();
  int p = tid & 31, ng = tid >> 5;
  float a0[8] = {}, a1[8] = {};
  for (int o = 0; o < 64; ++o) {
    float w0 = wl[o * 64 + p], w1 = wl[o * 64 + p + 32];
    float4 xa = *(const float4*)&xt[o * 64 + ng * 8];
    float4 xb = *(const float4*)&xt[o * 64 + ng * 8 + 4];
    float xv[8] = {xa.x, xa.y, xa.z, xa.w, xb.x, xb.y, xb.z, xb.w};
    #pragma unroll
    for (int j = 0; j < 8; ++j) { a0[j] = fmaf(w0, xv[j], a0[j]); a1[j] = fmaf(w1, xv[j], a1[j]); }
  }
  float fb0 = fb[p], fb1 = fb[p + 32];
  int obase = (b * T_ + t) * N_ + n0 + ng * 8;
  #pragma unroll
  for (int j = 0; j < 8; ++j) {
    out[(obase + j) * 64 + p]      = a0[j] + fb0;
    out[(obase + j) * 64 + p + 32] = a1[j] + fb1;
  }
}

extern "C" void kernel_launch(void* const* d_in, const int* in_sizes, int n_in,
                              void* d_out, int out_size, void* d_ws, size_t ws_size,
                              hipStream_t stream) {
  const float* x   = (const float*)d_in[0];
  const float* Lk  = (const float*)d_in[1];
  const float* th1 = (const float*)d_in[2];
  const float* b1  = (const float*)d_in[3];
  const float* th2 = (const float*)d_in[4];
  const float* b2  = (const float*)d_in[5];
  const float* fcw = (const float*)d_in[6];
  const float* fcb = (const float*)d_in[7];

  char* ws = (char*)d_ws;
  size_t off = 0;
  auto alloc = [&](size_t bytes) { size_t p = off; off += (bytes + 255) & ~(size_t)255; return p; };
  size_t oBt = alloc((size_t)KC_ * N_ * 2);
  size_t oTh = alloc((size_t)2 * 64 * 192 * 2);
  size_t oX2 = alloc((size_t)B_ * C_ * T_ * N_ * 2);
  size_t perB = (size_t)RPB * KC_ * 2;
  size_t avail = ws_size > off ? ws_size - off : 0;
  int NB = (int)(avail / perB);
  if (NB > B_) NB = B_;
  if (NB < 1) NB = 1;

  ushort_t* Bt = (ushort_t*)(ws + oBt);
  ushort_t* Th = (ushort_t*)(ws + oTh);
  ushort_t* X2 = (ushort_t*)(ws + oX2);
  ushort_t* Yb = (ushort_t*)(ws + off);
  ushort_t* X1 = (ushort_t*)d_out;

  prep_th<<<96, 256, 0, stream>>>(th1, th2, Th);
  prep_bt<<<1536, 256, 0, stream>>>(Lk, Bt);

  for (int b0 = 0; b0 < B_; b0 += NB) {
    int nb = (b0 + NB <= B_) ? NB : (B_ - b0);
    mix_kernel<0><<<nb * 96, 256, 0, stream>>>((const void*)x, Th, Yb, b0);
    gemm8p<0><<<dim3(16 * nb), 512, 0, stream>>>(Yb, Bt, (const void*)x, b1, X1, b0);
  }
  for (int b0 = 0; b0 < B_; b0 += NB) {
    int nb = (b0 + NB <= B_) ? NB : (B_ - b0);
    mix_kernel<1><<<nb * 96, 256, 0, stream>>>((const void*)X1, Th + 12288, Yb, b0);
    gemm8p<1><<<dim3(16 * nb), 512, 0, stream>>>(Yb, Bt, (const void*)X1, b2, X2, b0);
  }
  fc_kernel<<<32 * 12 * 16, 256, 0, stream>>>(X2, fcw, fcb, (float*)d_out);
}

// Round 5
// 503.575 us; speedup vs baseline: 1.5545x; 1.2977x over previous
//
#include <hip/hip_runtime.h>

typedef unsigned short ushort_t;
typedef unsigned long long u64;
typedef short short8 __attribute__((ext_vector_type(8)));
typedef float f32x4 __attribute__((ext_vector_type(4)));

#define B_   32
#define C_   64
#define T_   12
#define N_   1024
#define KS_  3
#define KC_  3072
#define RPB  768
#define NT_  48          // K-tiles of 64
#define BM_  192
#define LBUF 57344       // bytes per LDS buffer: A 192*64*2 (=24576) + B 256*64*2 (=32768)
#define ABYT 24576       // A region bytes (plane stride 12288)
#define BPLN 16384       // B plane stride

__device__ __forceinline__ float bf2f(ushort_t u) {
  union { unsigned u; float f; } v; v.u = ((unsigned)u) << 16; return v.f;
}
__device__ __forceinline__ ushort_t f2bf(float f) {
  union { float f; unsigned u; } v; v.f = f;
  unsigned r = v.u + 0x7FFFu + ((v.u >> 16) & 1u);
  return (ushort_t)(r >> 16);
}

__device__ __forceinline__ void gload16(const ushort_t* g, ushort_t* l) {
  __builtin_amdgcn_global_load_lds(
      (const __attribute__((address_space(1))) unsigned int*)g,
      (__attribute__((address_space(3))) unsigned int*)l, 16, 0, 0);
}

// ---------- prep: thA[l][k][o][i] = bf16(theta_l[i][o][k]) ----------
__global__ void prep_th(const float* __restrict__ th1, const float* __restrict__ th2,
                        ushort_t* __restrict__ out) {
  int id = blockIdx.x * 256 + threadIdx.x;          // 2*3*64*64 = 24576
  if (id >= 24576) return;
  int l = id / 12288, rem = id % 12288;
  int k = rem / 4096;
  int o = (rem >> 6) & 63;
  int i = rem & 63;
  const float* th = l ? th2 : th1;
  out[id] = f2bf(th[(i * 64 + o) * 3 + k]);
}

// ---------- prep: Bt[n][k*1024+m] = bf16(Lk[k][n][m]) ----------
__global__ void prep_bt(const float* __restrict__ Lk, ushort_t* __restrict__ Bt) {
  int id = blockIdx.x * 256 + threadIdx.x;
  int k = id >> 17, rem = id & 131071;
  int n = rem >> 7, mc = rem & 127;
  int m = mc << 3;
  const float* src = Lk + ((k * N_ + n) * N_ + m);
  float4 v0 = *(const float4*)src;
  float4 v1 = *(const float4*)(src + 4);
  short8 o8;
  o8[0] = (short)f2bf(v0.x); o8[1] = (short)f2bf(v0.y);
  o8[2] = (short)f2bf(v0.z); o8[3] = (short)f2bf(v0.w);
  o8[4] = (short)f2bf(v1.x); o8[5] = (short)f2bf(v1.y);
  o8[6] = (short)f2bf(v1.z); o8[7] = (short)f2bf(v1.w);
  *(short8*)&Bt[n * KC_ + k * N_ + m] = o8;
}

// ---------- MFMA channel mix: Y[(bl*12+t)*64+o][k*1024+m] = sum_i thA[k][o][i]*x[b,i,t,m] ----------
// Zero-LDS: B-operand (x^T, K=i) gathered per-lane from global (16 consecutive
// lanes read consecutive m -> 32-64B segments), held in regs across all 3 k.
// A-operand from thA[k][o][i] (i-contiguous, dwordx4, L2-hot).
// D mapping (verified in gemm): row(A-side o) = of*16 + l4*4 + r, col(B-side m) = mf*16 + l15.
template<int IN_BF16>
__global__ __launch_bounds__(256, 2)
void mix_mfma(const void* __restrict__ in, const ushort_t* __restrict__ thA,
              ushort_t* __restrict__ Y, int b0) {
  const int bid = blockIdx.x;           // nb*48: [bt][mq]
  const int mq = bid & 3;
  const int bt = bid >> 2;              // bl*12 + t
  const int bl = bt / 12, t = bt % 12;
  const int b = b0 + bl;
  const int tid = threadIdx.x;
  const int wv = tid >> 6, lane = tid & 63;
  const int l15 = lane & 15, l4 = lane >> 4;
  const int m0 = mq * 256 + wv * 64;

  const ushort_t* xg_b = (const ushort_t*)in;
  const float*    xg_f = (const float*)in;

  // B-frags: bfr[mf][ks], lane: x[i = ks*32 + l4*8 + j][m0 + mf*16 + l15]
  short8 bfr[4][2];
  #pragma unroll
  for (int mf = 0; mf < 4; ++mf) {
    const int m = m0 + mf * 16 + l15;
    #pragma unroll
    for (int ks = 0; ks < 2; ++ks) {
      #pragma unroll
      for (int j = 0; j < 8; ++j) {
        const int i = ks * 32 + l4 * 8 + j;
        const size_t adr = ((size_t)(b * C_ + i) * T_ + t) * N_ + m;
        ushort_t v = IN_BF16 ? xg_b[adr] : f2bf(xg_f[adr]);
        bfr[mf][ks][j] = (short)v;
      }
    }
  }

  const size_t rbase = (size_t)(bt * C_);   // Y row base (bl*12+t)*64
  #pragma unroll
  for (int k = 0; k < 3; ++k) {
    // A-frags: afr[of][ks], lane: thA[k][of*16 + l15][ks*32 + l4*8 ..+8]
    short8 afr[4][2];
    #pragma unroll
    for (int of = 0; of < 4; ++of)
      #pragma unroll
      for (int ks = 0; ks < 2; ++ks)
        afr[of][ks] = *(const short8*)&thA[(size_t)(k * 64 + of * 16 + l15) * 64 + ks * 32 + l4 * 8];

    f32x4 acc[4][4] = {};
    #pragma unroll
    for (int ks = 0; ks < 2; ++ks)
      #pragma unroll
      for (int of = 0; of < 4; ++of)
        #pragma unroll
        for (int mf = 0; mf < 4; ++mf)
          acc[of][mf] = __builtin_amdgcn_mfma_f32_16x16x32_bf16(afr[of][ks], bfr[mf][ks], acc[of][mf], 0, 0, 0);

    #pragma unroll
    for (int of = 0; of < 4; ++of)
      #pragma unroll
      for (int mf = 0; mf < 4; ++mf)
        #pragma unroll
        for (int r = 0; r < 4; ++r) {
          const int o = of * 16 + l4 * 4 + r;
          Y[(rbase + o) * KC_ + k * N_ + m0 + mf * 16 + l15] = f2bf(acc[of][mf][r]);
        }
  }
}

// ---------- 192x256-tile phased GEMM: C = Y @ Bt^T, epilogue bias+residual+relu ----------
// LDS per buffer: A [s:2][row:192][64B] (24576 B) then B [s:2][row:256][64B] (32768 B).
// Swizzle: stored col-byte = logical ^ (((row>>3)&1)<<5); applied on global source
// (write side, since global_load_lds dest must be linear) and on ds_read address.
// B-fragment read rows = wn*16 + nf*64 + l15 (frag stride 4096 B), matching
// the epilogue column mapping col = n0 + wn*16 + nf*64 + l15.

#define MFMA12(g)                                                                           \
  acc[3*(g)+0][0] = __builtin_amdgcn_mfma_f32_16x16x32_bf16(a0, b0, acc[3*(g)+0][0],0,0,0); \
  acc[3*(g)+0][1] = __builtin_amdgcn_mfma_f32_16x16x32_bf16(a0, b1, acc[3*(g)+0][1],0,0,0); \
  acc[3*(g)+0][2] = __builtin_amdgcn_mfma_f32_16x16x32_bf16(a0, b2, acc[3*(g)+0][2],0,0,0); \
  acc[3*(g)+0][3] = __builtin_amdgcn_mfma_f32_16x16x32_bf16(a0, b3, acc[3*(g)+0][3],0,0,0); \
  acc[3*(g)+1][0] = __builtin_amdgcn_mfma_f32_16x16x32_bf16(a1, b0, acc[3*(g)+1][0],0,0,0); \
  acc[3*(g)+1][1] = __builtin_amdgcn_mfma_f32_16x16x32_bf16(a1, b1, acc[3*(g)+1][1],0,0,0); \
  acc[3*(g)+1][2] = __builtin_amdgcn_mfma_f32_16x16x32_bf16(a1, b2, acc[3*(g)+1][2],0,0,0); \
  acc[3*(g)+1][3] = __builtin_amdgcn_mfma_f32_16x16x32_bf16(a1, b3, acc[3*(g)+1][3],0,0,0); \
  acc[3*(g)+2][0] = __builtin_amdgcn_mfma_f32_16x16x32_bf16(a2, b0, acc[3*(g)+2][0],0,0,0); \
  acc[3*(g)+2][1] = __builtin_amdgcn_mfma_f32_16x16x32_bf16(a2, b1, acc[3*(g)+2][1],0,0,0); \
  acc[3*(g)+2][2] = __builtin_amdgcn_mfma_f32_16x16x32_bf16(a2, b2, acc[3*(g)+2][2],0,0,0); \
  acc[3*(g)+2][3] = __builtin_amdgcn_mfma_f32_16x16x32_bf16(a2, b3, acc[3*(g)+2][3],0,0,0);

#define STAGE_A(kt, j) gload16(gA##j + (size_t)(kt) * 64,                                   \
    (ushort_t*)(lp + (((kt) & 1) ? LBUF : 0) + (j) * 8192 + wofs))
#define STAGE_B(kt, j) gload16(gB##j + (size_t)(kt) * 64,                                   \
    (ushort_t*)(lp + (((kt) & 1) ? LBUF : 0) + ABYT + (j) * 8192 + wofs))

#define LD8(p) (*(const short8*)(p))

template<int RES_BF16>
__global__ __launch_bounds__(512, 2)
void gemm8p(const ushort_t* __restrict__ Y, const ushort_t* __restrict__ Bt,
            const void* __restrict__ res, const float* __restrict__ bias,
            ushort_t* __restrict__ outb, int batch0) {
  // bijective XCD swizzle; gridDim.x = 16*nb is always a multiple of 8
  const int nwg = gridDim.x;
  int orig = blockIdx.x;
  int q8 = nwg >> 3;
  int wg = (orig & 7) * q8 + (orig >> 3);
  const int mtile = wg >> 2, ntile = wg & 3;

  const int tid = threadIdx.x;
  const int wid = tid >> 6, lane = tid & 63;
  const int wm = wid >> 2, wn = wid & 3;
  const int l15 = lane & 15, l4 = lane >> 4;

  __shared__ ushort_t LDSU[LBUF];   // 114688 bytes total (2 buffers)
  char* lp = (char*)LDSU;

  const int row0 = mtile * BM_;
  const int n0 = ntile * 256;
  const int wofs = wid * 1024;

  // staging source pointers (per-lane, swizzle pre-applied on global col)
  const int lam = lane >> 2, lc = lane & 3;
  const ushort_t *gA0, *gA1, *gA2, *gB0, *gB1, *gB2, *gB3;
  {
    int p, s, row, colel;
    p = 0 * 128 + wid * 16 + lam; s = p >= 192 ? 1 : 0; row = p - s * 192;
    colel = (lc * 8) ^ (((row >> 3) & 1) << 4);
    gA0 = Y + (size_t)(row0 + row) * KC_ + s * 32 + colel;
    p = 1 * 128 + wid * 16 + lam; s = p >= 192 ? 1 : 0; row = p - s * 192;
    colel = (lc * 8) ^ (((row >> 3) & 1) << 4);
    gA1 = Y + (size_t)(row0 + row) * KC_ + s * 32 + colel;
    p = 2 * 128 + wid * 16 + lam; s = p >= 192 ? 1 : 0; row = p - s * 192;
    colel = (lc * 8) ^ (((row >> 3) & 1) << 4);
    gA2 = Y + (size_t)(row0 + row) * KC_ + s * 32 + colel;
    p = 0 * 128 + wid * 16 + lam; s = p >> 8; row = p & 255;
    colel = (lc * 8) ^ (((row >> 3) & 1) << 4);
    gB0 = Bt + (size_t)(n0 + row) * KC_ + s * 32 + colel;
    p = 1 * 128 + wid * 16 + lam; s = p >> 8; row = p & 255;
    colel = (lc * 8) ^ (((row >> 3) & 1) << 4);
    gB1 = Bt + (size_t)(n0 + row) * KC_ + s * 32 + colel;
    p = 2 * 128 + wid * 16 + lam; s = p >> 8; row = p & 255;
    colel = (lc * 8) ^ (((row >> 3) & 1) << 4);
    gB2 = Bt + (size_t)(n0 + row) * KC_ + s * 32 + colel;
    p = 3 * 128 + wid * 16 + lam; s = p >> 8; row = p & 255;
    colel = (lc * 8) ^ (((row >> 3) & 1) << 4);
    gB3 = Bt + (size_t)(n0 + row) * KC_ + s * 32 + colel;
  }

  // read-side lane byte bases (swizzle XOR on col)
  const int swz = ((l15 >> 3) & 1) << 5;
  const int a_base = (wm * 16 + l15) * 64 + ((l4 * 16) ^ swz);
  const int b_base = ABYT + (wn * 16 + l15) * 64 + ((l4 * 16) ^ swz);

  // prologue: tile0 fully, tile1 minus A2
  STAGE_B(0, 0); STAGE_B(0, 1); STAGE_B(0, 2); STAGE_B(0, 3);
  STAGE_A(0, 0); STAGE_A(0, 1); STAGE_A(0, 2);
  STAGE_B(1, 0); STAGE_B(1, 1); STAGE_B(1, 2); STAGE_B(1, 3);
  STAGE_A(1, 0); STAGE_A(1, 1);
  asm volatile("s_waitcnt vmcnt(6)" ::: "memory");   // tile 0 landed
  __builtin_amdgcn_s_barrier();

  f32x4 acc[6][4] = {};
  short8 b0, b1, b2, b3;

  for (int u = 0; u < NT_; ++u) {
    const char* abp = lp + ((u & 1) ? LBUF : 0) + a_base;
    const char* bbp = lp + ((u & 1) ? LBUF : 0) + b_base;

    { // phase 0: (s=0, mf 0-2); stage A2(u+1) [its region sealed at ph3(u-1)]
      short8 a0 = LD8(abp);
      short8 a1 = LD8(abp + 2048);
      short8 a2 = LD8(abp + 4096);
      b0 = LD8(bbp);  b1 = LD8(bbp + 4096);  b2 = LD8(bbp + 8192);  b3 = LD8(bbp + 12288);
      if (u + 1 < NT_) STAGE_A(u + 1, 2);
      __builtin_amdgcn_s_barrier();
      __builtin_amdgcn_s_setprio(1);
      MFMA12(0)
      __builtin_amdgcn_s_setprio(0);
      __builtin_amdgcn_s_barrier();
    }
    { // phase 1: (s=0, mf 3-5); stage B0,B1(u+2) [B s0 sealed after ph0]
      short8 a0 = LD8(abp + 6144);
      short8 a1 = LD8(abp + 8192);
      short8 a2 = LD8(abp + 10240);
      if (u + 2 < NT_) { STAGE_B(u + 2, 0); STAGE_B(u + 2, 1); }
      __builtin_amdgcn_s_barrier();
      __builtin_amdgcn_s_setprio(1);
      MFMA12(1)
      __builtin_amdgcn_s_setprio(0);
      __builtin_amdgcn_s_barrier();
    }
    { // phase 2: (s=1, mf 0-2); no staging
      short8 a0 = LD8(abp + 12288);
      short8 a1 = LD8(abp + 12288 + 2048);
      short8 a2 = LD8(abp + 12288 + 4096);
      b0 = LD8(bbp + BPLN);  b1 = LD8(bbp + BPLN + 4096);
      b2 = LD8(bbp + BPLN + 8192);  b3 = LD8(bbp + BPLN + 12288);
      __builtin_amdgcn_s_barrier();
      __builtin_amdgcn_s_setprio(1);
      MFMA12(0)
      __builtin_amdgcn_s_setprio(0);
      __builtin_amdgcn_s_barrier();
    }
    { // phase 3: (s=1, mf 3-5); stage B2,B3,A0,A1(u+2); counted vmcnt
      short8 a0 = LD8(abp + 12288 + 6144);
      short8 a1 = LD8(abp + 12288 + 8192);
      short8 a2 = LD8(abp + 12288 + 10240);
      if (u + 2 < NT_) {
        STAGE_B(u + 2, 2); STAGE_B(u + 2, 3);
        STAGE_A(u + 2, 0); STAGE_A(u + 2, 1);
        asm volatile("s_waitcnt vmcnt(6)" ::: "memory");  // tile u+1 complete
      } else if (u + 2 == NT_) {
        asm volatile("s_waitcnt vmcnt(0)" ::: "memory");  // drain for last tile
      }
      __builtin_amdgcn_s_barrier();
      __builtin_amdgcn_s_setprio(1);
      MFMA12(1)
      __builtin_amdgcn_s_setprio(0);
      __builtin_amdgcn_s_barrier();
    }
  }

  // epilogue: bias + residual + relu, bf16 store
  const float*    resf = (const float*)res;
  const ushort_t* resb = (const ushort_t*)res;
  const int gb = batch0 + (mtile >> 2);
  const int rowb0 = (mtile & 3) * BM_;
  const int colb = n0 + wn * 16 + l15;
  #pragma unroll
  for (int mf = 0; mf < 6; ++mf) {
    #pragma unroll
    for (int r = 0; r < 4; ++r) {
      int rl = mf * 32 + wm * 16 + l4 * 4 + r;
      int rowb = rowb0 + rl;
      int t = rowb >> 6, o = rowb & 63;
      float bs = bias[o];
      size_t base = ((size_t)(gb * C_ + o) * T_ + t) * N_;
      #pragma unroll
      for (int nf = 0; nf < 4; ++nf) {
        int col = colb + nf * 64;
        float rv = RES_BF16 ? bf2f(resb[base + col]) : resf[base + col];
        float v = acc[mf][nf][r] + bs + rv;
        v = fmaxf(v, 0.0f);
        outb[base + col] = f2bf(v);
      }
    }
  }
}

// ---------- FC: out[b,t,n,o2] = sum_o fw[o2,o]*x2[b,o,t,n] + fb[o2] ----------
__global__ __launch_bounds__(256, 2)
void fc_kernel(const ushort_t* __restrict__ x2, const float* __restrict__ fw,
               const float* __restrict__ fb, float* __restrict__ out) {
  int bid = blockIdx.x;
  int nt = bid & 15, btid = bid >> 4;
  int t = btid % 12, b = btid / 12;
  int n0 = nt << 6;
  int tid = threadIdx.x;
  __shared__ float xt[64 * 64];
  __shared__ float wl[64 * 64];
  #pragma unroll
  for (int j = 0; j < 2; ++j) {
    int c = tid + j * 256;
    int row = c >> 3, col = (c & 7) << 3;
    short8 v = *(const short8*)&x2[((b * C_ + row) * T_ + t) * N_ + n0 + col];
    #pragma unroll
    for (int q = 0; q < 8; ++q) xt[row * 64 + col + q] = bf2f((ushort_t)v[q]);
  }
  #pragma unroll
  for (int j = 0; j < 4; ++j) {
    int c = tid + j * 256;
    int o2 = c >> 4, o4 = (c & 15) << 2;
    float4 v = *(const float4*)&fw[o2 * 64 + o4];
    wl[(o4 + 0) * 64 + o2] = v.x; wl[(o4 + 1) * 64 + o2] = v.y;
    wl[(o4 + 2) * 64 + o2] = v.z; wl[(o4 + 3) * 64 + o2] = v.w;
  }
  __syncthreads();
  int p = tid & 31, ng = tid >> 5;
  float a0[8] = {}, a1[8] = {};
  for (int o = 0; o < 64; ++o) {
    float w0 = wl[o * 64 + p], w1 = wl[o * 64 + p + 32];
    float4 xa = *(const float4*)&xt[o * 64 + ng * 8];
    float4 xb = *(const float4*)&xt[o * 64 + ng * 8 + 4];
    float xv[8] = {xa.x, xa.y, xa.z, xa.w, xb.x, xb.y, xb.z, xb.w};
    #pragma unroll
    for (int j = 0; j < 8; ++j) { a0[j] = fmaf(w0, xv[j], a0[j]); a1[j] = fmaf(w1, xv[j], a1[j]); }
  }
  float fb0 = fb[p], fb1 = fb[p + 32];
  int obase = (b * T_ + t) * N_ + n0 + ng * 8;
  #pragma unroll
  for (int j = 0; j < 8; ++j) {
    out[(obase + j) * 64 + p]      = a0[j] + fb0;
    out[(obase + j) * 64 + p + 32] = a1[j] + fb1;
  }
}

extern "C" void kernel_launch(void* const* d_in, const int* in_sizes, int n_in,
                              void* d_out, int out_size, void* d_ws, size_t ws_size,
                              hipStream_t stream) {
  const float* x   = (const float*)d_in[0];
  const float* Lk  = (const float*)d_in[1];
  const float* th1 = (const float*)d_in[2];
  const float* b1  = (const float*)d_in[3];
  const float* th2 = (const float*)d_in[4];
  const float* b2  = (const float*)d_in[5];
  const float* fcw = (const float*)d_in[6];
  const float* fcb = (const float*)d_in[7];

  char* ws = (char*)d_ws;
  size_t off = 0;
  auto alloc = [&](size_t bytes) { size_t p = off; off += (bytes + 255) & ~(size_t)255; return p; };
  size_t oBt = alloc((size_t)KC_ * N_ * 2);
  size_t oTh = alloc((size_t)2 * 3 * 64 * 64 * 2);
  size_t oX2 = alloc((size_t)B_ * C_ * T_ * N_ * 2);
  size_t perB = (size_t)RPB * KC_ * 2;
  size_t avail = ws_size > off ? ws_size - off : 0;
  int NB = (int)(avail / perB);
  if (NB > B_) NB = B_;
  if (NB < 1) NB = 1;

  ushort_t* Bt = (ushort_t*)(ws + oBt);
  ushort_t* Th = (ushort_t*)(ws + oTh);
  ushort_t* X2 = (ushort_t*)(ws + oX2);
  ushort_t* Yb = (ushort_t*)(ws + off);
  ushort_t* X1 = (ushort_t*)d_out;

  prep_th<<<96, 256, 0, stream>>>(th1, th2, Th);
  prep_bt<<<1536, 256, 0, stream>>>(Lk, Bt);

  for (int b0 = 0; b0 < B_; b0 += NB) {
    int nb = (b0 + NB <= B_) ? NB : (B_ - b0);
    mix_mfma<0><<<nb * 48, 256, 0, stream>>>((const void*)x, Th, Yb, b0);
    gemm8p<0><<<dim3(16 * nb), 512, 0, stream>>>(Yb, Bt, (const void*)x, b1, X1, b0);
  }
  for (int b0 = 0; b0 < B_; b0 += NB) {
    int nb = (b0 + NB <= B_) ? NB : (B_ - b0);
    mix_mfma<1><<<nb * 48, 256, 0, stream>>>((const void*)X1, Th + 12288, Yb, b0);
    gemm8p<1><<<dim3(16 * nb), 512, 0, stream>>>(Yb, Bt, (const void*)X1, b2, X2, b0);
  }
  fc_kernel<<<32 * 12 * 16, 256, 0, stream>>>(X2, fcw, fcb, (float*)d_out);
}